// Round 3
// baseline (940.303 us; speedup 1.0000x reference)
//
#include <hip/hip_runtime.h>
#include <cmath>

#define NN   1000
#define TT   4
#define PP   10
#define DD   13
#define FF   128
#define HH   128
#define EAA  16
#define KDIM 64
#define EE   20000
#define I_NODE 91
#define I_EDGE 169
#define MROW  13000            // N*D
#define OUT_FLOAT4 42250000L   // 13000*13000/4

// ---- K1 "front": one dispatch, role-split by blockIdx ----------------------
//   [0,640)        comb_edge: Wcomb[p][k][:] = W_edge[p][k][:] @ cob_edge[p]
//   [640,1152)     comb_node: Wnc[t][f][:]   = W_node[t][f][:] @ cob_node[t]
//   [1152,2152)    node_msg:  m = nf @ Wmsg ; agg = 0
//   [2152,10344)   zero M (grid-stride float4) — the 676MB fill; all other
//                  roles hide under its bandwidth shadow instead of
//                  serializing as separate dispatches.
#define NB_CE   640
#define NB_CN   512
#define NB_MSG  1000
#define NB_ZERO 8192
#define NB_FRONT (NB_CE + NB_CN + NB_MSG + NB_ZERO)

__global__ __launch_bounds__(256) void k_front(
    const float* __restrict__ We, const float* __restrict__ cobE,
    const float* __restrict__ Wn, const float* __restrict__ cobN,
    const float* __restrict__ nf, const float* __restrict__ Wmsg,
    float* __restrict__ Wcomb, float* __restrict__ Wnc,
    float* __restrict__ m, float* __restrict__ agg,
    float4* __restrict__ Mz) {
  int b = blockIdx.x, t = threadIdx.x;
  if (b < NB_CE) {                       // ---- comb_edge
    if (t < I_EDGE) {
      int pk = b, p = pk >> 6;
      float acc = 0.f;
      const float* wrow = We + pk * I_EDGE;
      const float* crow = cobE + p * I_EDGE * I_EDGE + t;
      for (int i = 0; i < I_EDGE; ++i) acc += wrow[i] * crow[i * I_EDGE];
      Wcomb[pk * I_EDGE + t] = acc;
    }
  } else if (b < NB_CE + NB_CN) {        // ---- comb_node
    if (t < I_EDGE) {
      int tf = b - NB_CE, ty = tf >> 7;
      float acc = 0.f;
      const float* wrow = Wn + tf * I_NODE;
      const float* crow = cobN + ty * I_NODE * I_EDGE + t;
      for (int i = 0; i < I_NODE; ++i) acc += wrow[i] * crow[i * I_EDGE];
      Wnc[tf * I_EDGE + t] = acc;
    }
  } else if (b < NB_CE + NB_CN + NB_MSG) {  // ---- node_msg + agg zero
    int n = b - (NB_CE + NB_CN);
    __shared__ float row[FF];
    if (t < FF) row[t] = nf[n * FF + t];
    __syncthreads();
    if (t < FF) {
      float acc = 0.f;
#pragma unroll 8
      for (int f = 0; f < FF; ++f) acc += row[f] * Wmsg[f * FF + t];
      m[n * FF + t] = acc;
    } else {
      agg[n * FF + (t - FF)] = 0.f;
    }
  } else {                               // ---- zero output matrix
    long base = (long)(b - (NB_CE + NB_CN + NB_MSG)) * 256 + t;
    const long stride = (long)NB_ZERO * 256;
    float4 z = make_float4(0.f, 0.f, 0.f, 0.f);
    for (long i = base; i < OUT_FLOAT4; i += stride) Mz[i] = z;
  }
}

// ---- K2: symmetric segment sum via atomics (agg L2-resident) ---------------
__global__ __launch_bounds__(256) void k_scatter(
    const float* __restrict__ m, const int* __restrict__ src,
    const int* __restrict__ dst, float* __restrict__ agg) {
  int idx = blockIdx.x * 256 + threadIdx.x;
  if (idx >= EE * FF) return;
  int e = idx >> 7, j = idx & 127;
  int s = src[e], d = dst[e];
  atomicAdd(&agg[d * FF + j], m[s * FF + j]);
  atomicAdd(&agg[s * FF + j], m[d * FF + j]);
}

// ---- K3: fused node_h + per-node precomputes (V1,V2,U) + diagonal block ----
// V1[n] = nh[n]@Wem[0:128], V2[n] = nh[n]@Wem[128:256]
// U[n][k] = nh[n]@Wproj[128:256], U[n][64+k] = nh[n]@Wproj[256:384]
// diag  = (nh[n]@Wnc[type]) scattered to M[n-block diagonal]
__global__ __launch_bounds__(192) void k_nodes(
    const float* __restrict__ nf, const float* __restrict__ agg,
    const float* __restrict__ na, const float* __restrict__ Wattr,
    const float* __restrict__ Wem, const float* __restrict__ Wproj,
    const int* __restrict__ ntype, const float* __restrict__ Wnc,
    float* __restrict__ nh, float* __restrict__ V1, float* __restrict__ V2,
    float* __restrict__ U, float* __restrict__ M) {
  int n = blockIdx.x, t = threadIdx.x;
  int ty = ntype[n];
  __shared__ float row[FF];
  if (t < FF) {
    float a = 0.f;
#pragma unroll
    for (int q = 0; q < TT; ++q) a += na[n * TT + q] * Wattr[q * FF + t];
    float v = nf[n * FF + t] + agg[n * FF + t] * (1.0f / 20.0f) + a;
    row[t] = v;
    nh[n * FF + t] = v;
  }
  __syncthreads();
  if (t < FF) {
    float v1 = 0.f, v2 = 0.f;
#pragma unroll 4
    for (int f = 0; f < FF; ++f) {
      float x = row[f];
      v1 += x * Wem[f * HH + t];
      v2 += x * Wem[(FF + f) * HH + t];
    }
    V1[n * HH + t] = v1;
    V2[n * HH + t] = v2;
    int k = t & 63, half = t >> 6;
    const float* W = Wproj + (FF + half * FF) * KDIM + k;
    float u = 0.f;
#pragma unroll 4
    for (int f = 0; f < FF; ++f) u += row[f] * W[f * KDIM];
    U[n * 128 + t] = u;
  }
  if (t < I_EDGE) {
    float acc = 0.f;
    const float* W = Wnc + ty * FF * I_EDGE + t;
#pragma unroll 4
    for (int f = 0; f < FF; ++f) acc += row[f] * W[f * I_EDGE];
    int x = t / DD, y = t % DD;
    atomicAdd(&M[(size_t)(n * DD + x) * MROW + (n * DD + y)], acc);
  }
}

// ---- K4: fully fused edge pipeline, 4 edges/block --------------------------
// em   = tanh(V1[s] + V2[d] + [ef,ea]@Wem[256:288])       (t<128)
// hm   = em @ Wproj[0:128]                                 (t<64)
// h_ij = hm + U[s][0:64] + U[d][64:128]; h_ji = swap(s,d)  (t<64)
// blk  = h @ Wcomb[p]; symm-transpose; atomic scatter      (t<169)
#define EB 4
__global__ __launch_bounds__(768) void k_edge_all(
    const float* __restrict__ V1, const float* __restrict__ V2,
    const float* __restrict__ U, const float* __restrict__ ef,
    const float* __restrict__ ea, const int* __restrict__ src,
    const int* __restrict__ dst, const int* __restrict__ etype,
    const float* __restrict__ Wem, const float* __restrict__ Wproj,
    const float* __restrict__ Wcomb, float* __restrict__ M) {
  int t = threadIdx.x;      // 0..191
  int ei = threadIdx.y;     // 0..3
  int e = blockIdx.x * EB + ei;
  int s = src[e], d = dst[e], p = etype[e];
  __shared__ __align__(16) float efa[EB][32];
  __shared__ __align__(16) float em[EB][HH];
  __shared__ __align__(16) float h[EB][2][KDIM];
  __shared__ __align__(16) float tji[EB][I_EDGE];

  if (t < 32) efa[ei][t] = (t < 16) ? ef[e * EAA + t] : ea[e * EAA + (t - 16)];
  __syncthreads();

  if (t < HH) {   // edge message
    float acc = V1[s * HH + t] + V2[d * HH + t];
#pragma unroll
    for (int c = 0; c < 32; ++c) acc += efa[ei][c] * Wem[(256 + c) * HH + t];
    em[ei][t] = tanhf(acc);
  }
  __syncthreads();

  if (t < KDIM) { // msg projection + h build (both orientations)
    float hm = 0.f;
    for (int f = 0; f < HH; f += 4) {
      float4 mv = *(const float4*)&em[ei][f];
      hm += mv.x * Wproj[(f + 0) * KDIM + t] + mv.y * Wproj[(f + 1) * KDIM + t]
          + mv.z * Wproj[(f + 2) * KDIM + t] + mv.w * Wproj[(f + 3) * KDIM + t];
    }
    h[ei][0][t] = hm + U[s * 128 + t] + U[d * 128 + 64 + t];
    h[ei][1][t] = hm + U[d * 128 + t] + U[s * 128 + 64 + t];
  }
  __syncthreads();

  float bij = 0.f, bji = 0.f;
  if (t < I_EDGE) {
    const float* W = Wcomb + p * KDIM * I_EDGE + t;
    for (int k = 0; k < KDIM; k += 4) {
      float4 hi = *(const float4*)&h[ei][0][k];
      float4 hj = *(const float4*)&h[ei][1][k];
      float w0 = W[(k + 0) * I_EDGE], w1 = W[(k + 1) * I_EDGE];
      float w2 = W[(k + 2) * I_EDGE], w3 = W[(k + 3) * I_EDGE];
      bij += hi.x * w0 + hi.y * w1 + hi.z * w2 + hi.w * w3;
      bji += hj.x * w0 + hj.y * w1 + hj.z * w2 + hj.w * w3;
    }
    tji[ei][t] = bji;
  }
  __syncthreads();
  if (t < I_EDGE) {
    int x = t / DD, y = t % DD;
    float eb = 0.5f * (bij + tji[ei][y * DD + x]);
    atomicAdd(&M[(size_t)(s * DD + x) * MROW + (d * DD + y)], eb);
    atomicAdd(&M[(size_t)(d * DD + y) * MROW + (s * DD + x)], eb);
  }
}

extern "C" void kernel_launch(void* const* d_in, const int* in_sizes, int n_in,
                              void* d_out, int out_size, void* d_ws, size_t ws_size,
                              hipStream_t stream) {
  const float* node_feats = (const float*)d_in[0];
  const float* node_attrs = (const float*)d_in[1];
  const float* edge_feats = (const float*)d_in[2];
  const float* edge_attrs = (const float*)d_in[3];
  const int*   edge_index = (const int*)d_in[4];
  const int*   node_types = (const int*)d_in[5];
  const int*   edge_types = (const int*)d_in[6];
  const float* W_msg  = (const float*)d_in[7];
  const float* W_attr = (const float*)d_in[8];
  const float* W_em   = (const float*)d_in[9];
  const float* W_proj = (const float*)d_in[10];
  const float* W_node = (const float*)d_in[11];
  const float* W_edge = (const float*)d_in[12];
  const float* cob_node = (const float*)d_in[13];
  const float* cob_edge = (const float*)d_in[14];

  float* M  = (float*)d_out;
  float* ws = (float*)d_ws;
  float* m_buf = ws;                  // N*F = 128000
  float* agg   = ws + 128000;         // N*F
  float* nh    = ws + 256000;         // N*F
  float* V1    = ws + 384000;         // N*H
  float* V2    = ws + 512000;         // N*H
  float* U     = ws + 640000;         // N*128
  float* Wcomb = ws + 768000;         // P*K*I_EDGE = 108,160
  float* Wnc   = ws + 876160;         // T*F*I_EDGE = 86,528 (end ~3.9 MB)

  const int* src = edge_index;        // edge_index[0]
  const int* dst = edge_index + EE;   // edge_index[1]

  k_front   <<<NB_FRONT, 256, 0, stream>>>(W_edge, cob_edge, W_node, cob_node,
                                           node_feats, W_msg, Wcomb, Wnc,
                                           m_buf, agg, (float4*)M);
  k_scatter <<<(EE * FF) / 256, 256, 0, stream>>>(m_buf, src, dst, agg);
  k_nodes   <<<NN, 192, 0, stream>>>(node_feats, agg, node_attrs, W_attr,
                                     W_em, W_proj, node_types, Wnc,
                                     nh, V1, V2, U, M);
  k_edge_all<<<dim3(EE / EB), dim3(192, 4), 0, stream>>>(V1, V2, U, edge_feats,
                                                         edge_attrs, src, dst,
                                                         edge_types, W_em, W_proj,
                                                         Wcomb, M);
}